// Round 1
// baseline (9544.975 us; speedup 1.0000x reference)
//
#include <hip/hip_runtime.h>
#include <hip/hip_bf16.h>
#include <math.h>

#define DEV __device__ __forceinline__

constexpr int NNODES = 16384;       // B*NPG
constexpr int NEDGE  = 262144;      // N*DEG
constexpr int NEL    = NEDGE + NNODES;
constexpr int FIN    = 256;
constexpr int C1     = 384;         // GH*EH
constexpr int DM     = 192;
constexpr int BZ     = 128;
constexpr int NPG_   = 128;
constexpr int LL     = 4;
constexpr int PP     = 32;
constexpr int SM     = 33;
constexpr int NH_    = 8;
constexpr int DH     = 24;
constexpr int DFF_   = 512;

// ---- workspace layout (float units) ----
constexpr size_t O_XP1  = 0;                                  // N*C1 ; later overlapped by bf16 CA-KV
constexpr size_t O_H    = O_XP1 + (size_t)NNODES*C1;
constexpr size_t O_XP2  = O_H   + (size_t)NNODES*C1;
constexpr size_t O_MEM  = O_XP2 + (size_t)NNODES*DM;
constexpr size_t SA_SZ  = (size_t)BZ*LL*SM*DM;
constexpr size_t O_KSA  = O_MEM + (size_t)NNODES*DM;
constexpr size_t O_VSA  = O_KSA + SA_SZ;
constexpr size_t PL     = 417792;                             // transposed weights per layer
constexpr size_t O_WT   = O_VSA + SA_SZ;
constexpr size_t WT_SZ  = PL*LL + 36864 + 49152;
constexpr size_t O_PE   = O_WT + WT_SZ;
constexpr size_t O_AL1S = O_PE + (size_t)SM*DM;
constexpr size_t O_AL1D = O_AL1S + (size_t)NNODES*4;
constexpr size_t O_AL2S = O_AL1D + (size_t)NNODES*4;
constexpr size_t O_AL2D = O_AL2S + NNODES;
constexpr size_t O_CNT  = O_AL2D + NNODES;
constexpr size_t O_BASE = O_CNT + NNODES;
constexpr size_t O_FILL = O_BASE + NNODES;
constexpr size_t O_CSRC = O_FILL + NNODES;
// total ~27.6M floats ~ 110.5 MB

DEV float gelu_f(float v) { return 0.5f*v*(1.0f + erff(v*0.7071067811865475f)); }

// ---------------- misc ----------------
__global__ void zero_kernel(float* adj, int* cnt, int* fill) {
  int i = blockIdx.x*256 + threadIdx.x;
  if (i < BZ*SM*SM) adj[i] = 0.f;
  if (i < NNODES) { cnt[i] = 0; fill[i] = 0; }
}

__global__ void pe_kernel(float* pe) {
  int idx = blockIdx.x*256 + threadIdx.x;
  if (idx >= SM*DM) return;
  int p = idx / DM, d = idx % DM;
  int i2 = d >> 1;
  float div = __expf((float)(2*i2) * (-9.210340371976184f / (float)DM)); // -ln(10000)/D
  float a = (float)p * div;
  pe[idx] = (d & 1) ? cosf(a) : sinf(a);
}

__global__ void transpose_kernel(const float* __restrict__ W, float* __restrict__ Wt, int R, int C) {
  int idx = blockIdx.x*256 + threadIdx.x;
  if (idx >= R*C) return;
  int o = idx / C, k = idx % C;
  Wt[(size_t)k*R + o] = W[idx];
}

// ---------------- generic fp32 GEMM: C[M,N] = A[M,K] @ W[N,K]^T (+bias) ----------------
template<bool BIAS, bool BF16OUT>
__global__ __launch_bounds__(256) void gemm_nt(const float* __restrict__ A,
    const float* __restrict__ W, const float* __restrict__ bias,
    float* __restrict__ Cf, __hip_bfloat16* __restrict__ Cb, int M, int N, int K)
{
  __shared__ float As[16][68];
  __shared__ float Ws[16][68];
  const int bm = blockIdx.y*64, bn = blockIdx.x*64;
  const int t = threadIdx.x, tx = t & 15, ty = t >> 4;
  float acc[4][4] = {};
  for (int k0 = 0; k0 < K; k0 += 16) {
    #pragma unroll
    for (int i = 0; i < 4; ++i) {
      int idx = t + i*256, kk = idx & 15, m = idx >> 4;
      As[kk][m] = A[(size_t)(bm+m)*K + k0+kk];
      Ws[kk][m] = W[(size_t)(bn+m)*K + k0+kk];
    }
    __syncthreads();
    #pragma unroll
    for (int kk = 0; kk < 16; ++kk) {
      const float4 a4 = *(const float4*)&As[kk][ty*4];
      const float4 b4 = *(const float4*)&Ws[kk][tx*4];
      const float av[4] = {a4.x,a4.y,a4.z,a4.w};
      const float bv[4] = {b4.x,b4.y,b4.z,b4.w};
      #pragma unroll
      for (int i = 0; i < 4; ++i)
        #pragma unroll
        for (int j = 0; j < 4; ++j)
          acc[i][j] = fmaf(av[i], bv[j], acc[i][j]);
    }
    __syncthreads();
  }
  #pragma unroll
  for (int i = 0; i < 4; ++i) {
    const int m = bm + ty*4 + i;
    #pragma unroll
    for (int j = 0; j < 4; ++j) {
      const int n = bn + tx*4 + j;
      float v = acc[i][j];
      if (BIAS) v += bias[n];
      if (BF16OUT) Cb[(size_t)m*N + n] = __float2bfloat16(v);
      else         Cf[(size_t)m*N + n] = v;
    }
  }
}

// ---------------- GAT helpers ----------------
template<int HEADS, int CH>
__global__ void al_kernel(const float* __restrict__ xp, const float* __restrict__ asrc,
                          const float* __restrict__ adst, float* als, float* ald) {
  int idx = blockIdx.x*256 + threadIdx.x;
  if (idx >= NNODES*HEADS) return;
  int n = idx / HEADS, h = idx % HEADS;
  const float* row = xp + (size_t)n*(HEADS*CH) + h*CH;
  float s = 0, d = 0;
  for (int c = 0; c < CH; ++c) { float v = row[c]; s = fmaf(v, asrc[h*CH+c], s); d = fmaf(v, adst[h*CH+c], d); }
  als[idx] = s; ald[idx] = d;
}

__global__ void count_kernel(const int* __restrict__ dst, int* cnt) {
  int e = blockIdx.x*256 + threadIdx.x;
  if (e < NEDGE) atomicAdd(&cnt[dst[e]], 1);
}

__global__ __launch_bounds__(1024) void scan_kernel(const int* __restrict__ cnt, int* base) {
  __shared__ int tot[1024];
  int t = threadIdx.x;
  int local[16]; int s = 0;
  #pragma unroll
  for (int i = 0; i < 16; ++i) { int v = cnt[t*16+i] + 1; local[i] = s; s += v; }
  tot[t] = s; __syncthreads();
  if (t == 0) { int r = 0; for (int i = 0; i < 1024; ++i) { int v = tot[i]; tot[i] = r; r += v; } }
  __syncthreads();
  int off = tot[t];
  #pragma unroll
  for (int i = 0; i < 16; ++i) base[t*16+i] = off + local[i];
}

__global__ void scatter_kernel(const int* __restrict__ src, const int* __restrict__ dst,
                               const int* __restrict__ base, int* fill, int* csrc) {
  int e = blockIdx.x*256 + threadIdx.x;
  if (e < NEDGE) {
    int d = dst[e];
    int p = atomicAdd(&fill[d], 1);
    csrc[base[d] + p] = src[e];
  } else if (e < NEL) {
    int n = e - NEDGE;
    int p = atomicAdd(&fill[n], 1);
    csrc[base[n] + p] = n;   // self loop
  }
}

template<int HEADS, int CH, bool ELU>
__global__ __launch_bounds__(128) void agg_kernel(const float* __restrict__ xp,
    const float* __restrict__ als, const float* __restrict__ ald,
    const int* __restrict__ cnt, const int* __restrict__ base, const int* __restrict__ csrc,
    const float* __restrict__ bias, float* __restrict__ out)
{
  constexpr int CO = HEADS*CH;
  constexpr int MAXD = 128;
  int n = blockIdx.x, t = threadIdx.x;
  int deg = cnt[n] + 1, st = base[n];
  if (deg > MAXD) deg = MAXD;   // statistically impossible (lambda=16)
  __shared__ int   srcs[MAXD];
  __shared__ float ex[MAXD][HEADS];
  __shared__ float den[HEADS];
  for (int j = t; j < deg; j += 128) srcs[j] = csrc[st + j];
  __syncthreads();
  for (int idx = t; idx < deg*HEADS; idx += 128) {
    int j = idx / HEADS, h = idx % HEADS;
    float e = als[srcs[j]*HEADS + h] + ald[n*HEADS + h];
    ex[j][h] = (e > 0.f) ? e : 0.2f*e;   // leaky_relu(0.2)
  }
  __syncthreads();
  if (t < HEADS) {
    float m = -1e30f;
    for (int j = 0; j < deg; ++j) m = fmaxf(m, ex[j][t]);
    float s = 0;
    for (int j = 0; j < deg; ++j) { float v = __expf(ex[j][t]-m); ex[j][t] = v; s += v; }
    den[t] = 1.0f/(s + 1e-16f);
  }
  __syncthreads();
  for (int c = t; c < CO; c += 128) {
    int h = c / CH;
    float acc = 0;
    for (int j = 0; j < deg; ++j) acc = fmaf(ex[j][h], xp[(size_t)srcs[j]*CO + c], acc);
    float v = acc*den[h] + bias[c];
    if (ELU) v = (v > 0.f) ? v : (__expf(v) - 1.0f);
    out[(size_t)n*CO + c] = v;
  }
}

// ---------------- decode ----------------
DEV void ln_apply(const float* y, float* xo, int t, const float* g, const float* bta, float* red) {
  float v = (t < DM) ? y[t] : 0.f;
  float s = v, q = v*v;
  #pragma unroll
  for (int o = 32; o; o >>= 1) { s += __shfl_down(s, o, 64); q += __shfl_down(q, o, 64); }
  if ((t & 63) == 0) { red[t>>6] = s; red[8 + (t>>6)] = q; }
  __syncthreads();
  float S = red[0]+red[1]+red[2]+red[3];
  float Q = red[8]+red[9]+red[10]+red[11];
  float mu = S * (1.0f/DM);
  float var = Q * (1.0f/DM) - mu*mu;
  float rstd = rsqrtf(var + 1e-5f);
  if (t < DM) xo[t] = (y[t]-mu)*rstd*g[t] + bta[t];
  __syncthreads();
}

__global__ __launch_bounds__(256) void decode_kernel(
    const float* __restrict__ mem, const __hip_bfloat16* __restrict__ kv,
    const float* __restrict__ wt, const float* __restrict__ pe,
    float* __restrict__ ksa, float* __restrict__ vsa,
    const int* __restrict__ tgt_idx,
    const float* __restrict__ saqkvb, const float* __restrict__ saoutb,
    const float* __restrict__ caqkvb, const float* __restrict__ caoutb,
    const float* __restrict__ ff1b, const float* __restrict__ ff2b,
    const float* __restrict__ lng, const float* __restrict__ lnb,
    const float* __restrict__ h1b, const float* __restrict__ h2b,
    float* __restrict__ feats, float* __restrict__ adj)
{
  const int b = blockIdx.x, t = threadIdx.x;
  const int h = t >> 5, t32 = t & 31;
  __shared__ float lasts[SM][200];       // padded (192%32==0 would be 32-way conflicted)
  __shared__ float x[DM], y[DM], qkv[3*DM], attno[DM], hid[DFF_];
  __shared__ float prob[NH_][SM+3];
  __shared__ float cprob[NH_][NPG_];
  __shared__ float red[16];
  const float scl = 0.2041241452319315f; // 1/sqrt(24)

  const float* tgt0 = mem + ((size_t)b*NPG_ + tgt_idx[b])*DM;

  for (int i = 0; i < PP; ++i) {
    if (t < DM) x[t] = ((i == 0) ? tgt0[t] : lasts[i-1][t]) + pe[i*DM + t];
    __syncthreads();
    for (int l = 0; l < LL; ++l) {
      const float* Wq  = wt + (size_t)l*PL;
      const float* Wo  = Wq + 110592;
      const float* Wcq = Wq + 147456;
      const float* Wco = Wq + 184320;
      const float* W1  = Wq + 221184;
      const float* W2  = Wq + 319488;
      // --- SA qkv (576 outputs) ---
      for (int o = t; o < 3*DM; o += 256) {
        float a = saqkvb[l*3*DM + o];
        for (int k = 0; k < DM; ++k) a = fmaf(x[k], Wq[(size_t)k*576 + o], a);
        qkv[o] = a;
      }
      __syncthreads();
      float* Kb = ksa + ((size_t)(b*LL + l)*SM)*DM;
      float* Vb = vsa + ((size_t)(b*LL + l)*SM)*DM;
      if (t < DM) { Kb[(size_t)i*DM + t] = qkv[DM+t]; Vb[(size_t)i*DM + t] = qkv[2*DM+t]; }
      __syncthreads();
      // --- SA attention (causal; keys 0..i from cache) ---
      for (int j = t32; j <= i; j += 32) {
        float s = 0;
        for (int d = 0; d < DH; ++d) s = fmaf(qkv[h*DH+d], Kb[(size_t)j*DM + h*DH + d], s);
        prob[h][j] = s * scl;
      }
      __syncthreads();
      if (t32 == 0) {
        float m = -1e30f;
        for (int j = 0; j <= i; ++j) m = fmaxf(m, prob[h][j]);
        float s = 0;
        for (int j = 0; j <= i; ++j) { float e = __expf(prob[h][j]-m); prob[h][j] = e; s += e; }
        prob[h][SM] = 1.f/s;
      }
      __syncthreads();
      if (t32 < DH) {
        float inv = prob[h][SM], a = 0;
        for (int j = 0; j <= i; ++j) a = fmaf(prob[h][j], Vb[(size_t)j*DM + h*DH + t32], a);
        attno[h*DH + t32] = a * inv;
      }
      __syncthreads();
      // --- SA out-proj + residual ---
      if (t < DM) {
        float a = saoutb[l*DM + t];
        for (int k = 0; k < DM; ++k) a = fmaf(attno[k], Wo[(size_t)k*DM + t], a);
        y[t] = x[t] + a;
      }
      __syncthreads();
      ln_apply(y, x, t, lng + (l*3+0)*DM, lnb + (l*3+0)*DM, red);
      // --- CA q ---
      if (t < DM) {
        float a = caqkvb[l*3*DM + t];
        for (int k = 0; k < DM; ++k) a = fmaf(x[k], Wcq[(size_t)k*DM + t], a);
        qkv[t] = a;
      }
      __syncthreads();
      // --- CA attention over 128 memory keys (precomputed bf16 K/V) ---
      const __hip_bfloat16* KVb = kv + ((size_t)l*NNODES + (size_t)b*NPG_)*384;
      for (int j = t32; j < NPG_; j += 32) {
        const __hip_bfloat16* Kj = KVb + (size_t)j*384 + h*DH;
        float s = 0;
        for (int d = 0; d < DH; ++d) s = fmaf(qkv[h*DH+d], __bfloat162float(Kj[d]), s);
        cprob[h][j] = s * scl;
      }
      __syncthreads();
      {
        float lm = -1e30f;
        for (int j = t32; j < NPG_; j += 32) lm = fmaxf(lm, cprob[h][j]);
        #pragma unroll
        for (int m = 16; m; m >>= 1) lm = fmaxf(lm, __shfl_xor(lm, m, 64));
        float lsum = 0;
        for (int j = t32; j < NPG_; j += 32) { float e = __expf(cprob[h][j]-lm); cprob[h][j] = e; lsum += e; }
        #pragma unroll
        for (int m = 16; m; m >>= 1) lsum += __shfl_xor(lsum, m, 64);
        __syncthreads();
        if (t32 < DH) {
          float inv = 1.0f/lsum, a = 0;
          for (int j = 0; j < NPG_; ++j)
            a = fmaf(cprob[h][j], __bfloat162float(KVb[(size_t)j*384 + DM + h*DH + t32]), a);
          attno[h*DH + t32] = a * inv;
        }
      }
      __syncthreads();
      // --- CA out-proj + residual ---
      if (t < DM) {
        float a = caoutb[l*DM + t];
        for (int k = 0; k < DM; ++k) a = fmaf(attno[k], Wco[(size_t)k*DM + t], a);
        y[t] = x[t] + a;
      }
      __syncthreads();
      ln_apply(y, x, t, lng + (l*3+1)*DM, lnb + (l*3+1)*DM, red);
      // --- FFN ---
      for (int o = t; o < DFF_; o += 256) {
        float a = ff1b[l*DFF_ + o];
        for (int k = 0; k < DM; ++k) a = fmaf(x[k], W1[(size_t)k*DFF_ + o], a);
        hid[o] = gelu_f(a);
      }
      __syncthreads();
      if (t < DM) {
        float a = ff2b[l*DM + t];
        for (int k = 0; k < DFF_; ++k) a = fmaf(hid[k], W2[(size_t)k*DM + t], a);
        y[t] = x[t] + a;
      }
      __syncthreads();
      ln_apply(y, x, t, lng + (l*3+2)*DM, lnb + (l*3+2)*DM, red);
    }
    // --- head + adjacency ---
    if (t < DM) lasts[i][t] = x[t];
    __syncthreads();
    const float* H1t = wt + PL*LL;
    const float* H2t = H1t + 36864;
    if (t < DM) {
      float a = h1b[t];
      for (int k = 0; k < DM; ++k) a = fmaf(x[k], H1t[(size_t)k*DM + t], a);
      hid[t] = gelu_f(a);
    }
    __syncthreads();
    {
      float a = h2b[t];
      for (int k = 0; k < DM; ++k) a = fmaf(hid[k], H2t[(size_t)k*256 + t], a);
      feats[((size_t)b*PP + i)*256 + t] = a;
    }
    // cl[j] = lasts[j] . lasts[i]; only triu-surviving entries are written
    if (t <= i) {
      float a = 0;
      for (int d = 0; d < DM; ++d) a = fmaf(lasts[t][d], lasts[i][d], a);
      if (t == 0) {
        adj[((size_t)b*SM + i)*SM + 32] = a;
        adj[((size_t)b*SM + 32)*SM + i] = a;
      } else {
        int j2 = t - 1;
        adj[((size_t)b*SM + j2)*SM + i] = a;
        adj[((size_t)b*SM + i)*SM + j2] = a;
      }
    }
    __syncthreads();
  }
}

// ---------------- launch ----------------
extern "C" void kernel_launch(void* const* d_in, const int* in_sizes, int n_in,
                              void* d_out, int out_size, void* d_ws, size_t ws_size,
                              hipStream_t stream) {
  (void)in_sizes; (void)n_in; (void)out_size; (void)ws_size;
  const float* x_in    = (const float*)d_in[0];
  const int*   ei      = (const int*)d_in[1];
  const int*   tgt_idx = (const int*)d_in[2];
  const float* gat1_w  = (const float*)d_in[5];
  const float* g1as    = (const float*)d_in[6];
  const float* g1ad    = (const float*)d_in[7];
  const float* g1b     = (const float*)d_in[8];
  const float* gat2_w  = (const float*)d_in[9];
  const float* g2as    = (const float*)d_in[10];
  const float* g2ad    = (const float*)d_in[11];
  const float* g2b     = (const float*)d_in[12];
  const float* saqkvw  = (const float*)d_in[13];
  const float* saqkvb  = (const float*)d_in[14];
  const float* saoutw  = (const float*)d_in[15];
  const float* saoutb  = (const float*)d_in[16];
  const float* caqkvw  = (const float*)d_in[17];
  const float* caqkvb  = (const float*)d_in[18];
  const float* caoutw  = (const float*)d_in[19];
  const float* caoutb  = (const float*)d_in[20];
  const float* ff1w    = (const float*)d_in[21];
  const float* ff1b    = (const float*)d_in[22];
  const float* ff2w    = (const float*)d_in[23];
  const float* ff2b    = (const float*)d_in[24];
  const float* lng     = (const float*)d_in[25];
  const float* lnb     = (const float*)d_in[26];
  const float* h1w     = (const float*)d_in[27];
  const float* h1b     = (const float*)d_in[28];
  const float* h2w     = (const float*)d_in[29];
  const float* h2b     = (const float*)d_in[30];

  float* ws  = (float*)d_ws;
  float* out = (float*)d_out;
  float* adj = out + (size_t)BZ*PP*256;

  const int* src = ei;
  const int* dst = ei + NEDGE;

  int* cnt  = (int*)(ws + O_CNT);
  int* base = (int*)(ws + O_BASE);
  int* fill = (int*)(ws + O_FILL);
  int* csrc = (int*)(ws + O_CSRC);

  hipLaunchKernelGGL(zero_kernel, dim3(545), dim3(256), 0, stream, adj, cnt, fill);

  // GAT1: xp1 = x @ W1^T
  hipLaunchKernelGGL((gemm_nt<false,false>), dim3(C1/64, NNODES/64), dim3(256), 0, stream,
                     x_in, gat1_w, (const float*)nullptr, ws + O_XP1, (__hip_bfloat16*)nullptr,
                     NNODES, C1, FIN);
  hipLaunchKernelGGL((al_kernel<4,96>), dim3(NNODES*4/256), dim3(256), 0, stream,
                     ws+O_XP1, g1as, g1ad, ws+O_AL1S, ws+O_AL1D);
  hipLaunchKernelGGL(count_kernel, dim3(NEDGE/256), dim3(256), 0, stream, dst, cnt);
  hipLaunchKernelGGL(scan_kernel, dim3(1), dim3(1024), 0, stream, cnt, base);
  hipLaunchKernelGGL(scatter_kernel, dim3(NEL/256), dim3(256), 0, stream, src, dst, base, fill, csrc);
  hipLaunchKernelGGL((agg_kernel<4,96,true>), dim3(NNODES), dim3(128), 0, stream,
                     ws+O_XP1, ws+O_AL1S, ws+O_AL1D, cnt, base, csrc, g1b, ws+O_H);

  // GAT2
  hipLaunchKernelGGL((gemm_nt<false,false>), dim3(DM/64, NNODES/64), dim3(256), 0, stream,
                     ws+O_H, gat2_w, (const float*)nullptr, ws+O_XP2, (__hip_bfloat16*)nullptr,
                     NNODES, DM, C1);
  hipLaunchKernelGGL((al_kernel<1,192>), dim3(NNODES/256), dim3(256), 0, stream,
                     ws+O_XP2, g2as, g2ad, ws+O_AL2S, ws+O_AL2D);
  hipLaunchKernelGGL((agg_kernel<1,192,false>), dim3(NNODES), dim3(128), 0, stream,
                     ws+O_XP2, ws+O_AL2S, ws+O_AL2D, cnt, base, csrc, g2b, ws+O_MEM);

  // transposed decode weights
  auto T = [&](const float* Wsrc, float* Wt, int R, int Cc) {
    hipLaunchKernelGGL(transpose_kernel, dim3((R*Cc+255)/256), dim3(256), 0, stream, Wsrc, Wt, R, Cc);
  };
  for (int l = 0; l < LL; ++l) {
    float* bl = ws + O_WT + (size_t)l*PL;
    T(saqkvw + (size_t)l*576*192, bl,          576, 192);
    T(saoutw + (size_t)l*192*192, bl+110592,   192, 192);
    T(caqkvw + (size_t)l*576*192, bl+147456,   192, 192);  // first 192 rows = Wq
    T(caoutw + (size_t)l*192*192, bl+184320,   192, 192);
    T(ff1w   + (size_t)l*512*192, bl+221184,   512, 192);
    T(ff2w   + (size_t)l*192*512, bl+319488,   192, 512);
  }
  T(h1w, ws + O_WT + PL*LL,         192, 192);
  T(h2w, ws + O_WT + PL*LL + 36864, 256, 192);

  hipLaunchKernelGGL(pe_kernel, dim3((SM*DM+255)/256), dim3(256), 0, stream, ws+O_PE);

  // CA K/V hoisted: KV[l] = mem @ [Wk;Wv]^T + [bk;bv]  (bf16, overlaps dead xp1/h region)
  __hip_bfloat16* kvb = (__hip_bfloat16*)ws;
  for (int l = 0; l < LL; ++l) {
    hipLaunchKernelGGL((gemm_nt<true,true>), dim3(384/64, NNODES/64), dim3(256), 0, stream,
                       ws+O_MEM, caqkvw + (size_t)l*576*192 + (size_t)192*192,
                       caqkvb + l*576 + 192, (float*)nullptr,
                       kvb + (size_t)l*NNODES*384, NNODES, 384, DM);
  }

  hipLaunchKernelGGL(decode_kernel, dim3(BZ), dim3(256), 0, stream,
                     ws+O_MEM, kvb, ws+O_WT, ws+O_PE, ws+O_KSA, ws+O_VSA, tgt_idx,
                     saqkvb, saoutb, caqkvb, caoutb, ff1b, ff2b, lng, lnb, h1b, h2b,
                     out, adj);
}